// Round 10
// baseline (503.146 us; speedup 1.0000x reference)
//
#include <hip/hip_runtime.h>
#include <hip/hip_bf16.h>
#include <math.h>

// Fused GNN readout via bf16 MFMA (v_mfma_f32_32x32x16_bf16):
//   feat1 = relu(concat(h,x) @ W1 + b1)   [N,256]  GEMM1: K=400 (25 k-steps), A=bf16 hi, B=W1 hi ONLY
//   feat2 = relu(feat1 @ W2 + b2)         [N,64]   GEMM2: K=256, A=bf16 hi, B=W2 hi+lo
//   s_n   = feat2 . Wout ; out = sigmoid(segment_sum(s_n) + bout)
// R10: break the per-SSTEP latency chain:
//   - W1 hi-only: 4 MFMA/SSTEP, half the B traffic (L2 floor 40->20us) and
//     half the GEMM1 matrix content (42->21us). Error adds in quadrature to
//     the existing A-rounding term (predicted absmax ~2.3e-6 vs 7.8e-6 thr).
//   - B register pipeline DEPTH 4 (cover > L2 latency ~225cyc).
//   - A-fragment ds_reads prefetched 1 SSTEP ahead (fp32 regs, cvt at use).
//   - 3-ring counted-vmcnt (never 0 in loop), no setprio (m190).

typedef __attribute__((ext_vector_type(8)))  short short8v;
typedef __attribute__((ext_vector_type(16))) float f32x16;

#define G_NUM 2048
#define HID 200
#define EMB 200
#define DIN 400
#define NH1 256
#define NH2 64
#define BM  64
#define NKS1 25        // K=400 = 25 k-steps of 16, exact
#define NKS2 16        // K-steps for GEMM2 (K=256)

#define W1P_SH8 (NKS1*8*64)   // 12800 fragments (16B each), hi plane only
#define W2P_SH8 (NKS2*2*64)   // 2048

__device__ __forceinline__ unsigned short f2bf(float f) {
    union { float f; unsigned u; } v; v.f = f;
    unsigned r = v.u + 0x7fffu + ((v.u >> 16) & 1u);   // RNE
    return (unsigned short)(r >> 16);
}
__device__ __forceinline__ float bf2f(unsigned short b) {
    union { unsigned u; float f; } v; v.u = ((unsigned)b) << 16;
    return v.f;
}
// 8 fp32 -> 8 bf16 (RNE) via packed converts
__device__ __forceinline__ short8v cvt8(float4 a, float4 b) {
    union { __hip_bfloat162 q[4]; short8v s8; } u;
    u.q[0] = __float22bfloat162_rn(make_float2(a.x, a.y));
    u.q[1] = __float22bfloat162_rn(make_float2(a.z, a.w));
    u.q[2] = __float22bfloat162_rn(make_float2(b.x, b.y));
    u.q[3] = __float22bfloat162_rn(make_float2(b.z, b.w));
    return u.s8;
}

// Pre-pack W1 (hi only) / W2 (hi+lo) into MFMA-fragment order.
// Fragment (ks, ntile, lane) holds 8 bf16: B[k0+j][col], k0=ks*16+(lane>>5)*8,
// col=ntile*32+(lane&31). Contiguous-8 k in BOTH A and B => any consistent
// hw k-permutation cancels in the dot product.
__global__ void pack_weights(const float* __restrict__ W1, const float* __restrict__ W2,
                             unsigned short* __restrict__ w1h,
                             unsigned short* __restrict__ w2h, unsigned short* __restrict__ w2l)
{
    int idx = blockIdx.x * 256 + threadIdx.x;
    if (idx < W1P_SH8) {
        int l  = idx & 63;
        int nt = (idx >> 6) & 7;
        int ks = idx >> 9;
        int col = nt * 32 + (l & 31);
        int k0  = ks * 16 + (l >> 5) * 8;
        short8v H;
        #pragma unroll
        for (int j = 0; j < 8; ++j) H[j] = (short)f2bf(W1[(size_t)(k0 + j) * NH1 + col]);
        ((short8v*)w1h)[idx] = H;
    } else if (idx < W1P_SH8 + W2P_SH8) {
        int i2 = idx - W1P_SH8;
        int l  = i2 & 63;
        int nt = (i2 >> 6) & 1;
        int ks = i2 >> 7;
        int col = nt * 32 + (l & 31);
        int k0  = ks * 16 + (l >> 5) * 8;
        short8v H, L;
        #pragma unroll
        for (int j = 0; j < 8; ++j) {
            float v = W2[(size_t)(k0 + j) * NH2 + col];
            unsigned short hh = f2bf(v);
            H[j] = (short)hh;
            L[j] = (short)f2bf(v - bf2f(hh));
        }
        ((short8v*)w2h)[i2] = H;
        ((short8v*)w2l)[i2] = L;
    }
}

__launch_bounds__(256, 3)
__global__ void fused_readout(const float* __restrict__ h, const float* __restrict__ x,
                              const int* __restrict__ batch,
                              const unsigned short* __restrict__ w1h,
                              const unsigned short* __restrict__ w2h, const unsigned short* __restrict__ w2l,
                              const float* __restrict__ b1, const float* __restrict__ b2,
                              const float* __restrict__ Wout, const float* __restrict__ zbuf,
                              float* __restrict__ gf1d, int N)
{
    // 49152 B LDS: 3 DISJOINT ring buffers, 16 KiB each ([64 rows][64 fp32],
    // row stride 256B, 16B-granule XOR swizzle c16 ^= row&15 applied on the
    // GLOBAL SOURCE; LDS dest linear for global_load_lds). Chunk c -> ring c%3,
    // issued 2 chunks ahead. After the k-loop (full __syncthreads):
    // F1h rows 0-31 -> R0, rows 32-63 -> R1; s2p/srow -> R2.
    __shared__ __align__(16) float R0[4096];
    __shared__ __align__(16) float R1[4096];
    __shared__ __align__(16) float R2[4096];

    const int t    = threadIdx.x;
    const int lane = t & 63;
    const int w    = t >> 6;
    const int n0   = blockIdx.x * BM;
    const int l31  = lane & 31;
    const int hs   = lane >> 5;         // k-half select

    const short8v* W1H = (const short8v*)w1h;

    f32x16 acc00, acc01, acc10, acc11;
    #pragma unroll
    for (int r = 0; r < 16; ++r) { acc00[r] = 0.f; acc01[r] = 0.f; acc10[r] = 0.f; acc11[r] = 0.f; }

    // ---- helpers ----
    #define AISSUE(CH, RP) do {                                                \
        _Pragma("unroll")                                                      \
        for (int ii = 0; ii < 4; ++ii) {                                       \
            int brow = w*16 + ii*4;                                            \
            int row  = brow + (lane >> 4);                                     \
            int node = n0 + row;                                               \
            int colf = (CH)*64 + (((lane & 15) ^ (row & 15)) << 2);            \
            const float* src;                                                  \
            if (node >= N || colf >= DIN) src = zbuf + (lane & 15)*4;          \
            else if (colf < HID)          src = h + (size_t)node*HID + colf;   \
            else                          src = x + (size_t)node*EMB + (colf - HID); \
            __builtin_amdgcn_global_load_lds(                                  \
                (const __attribute__((address_space(1))) unsigned*)src,        \
                (__attribute__((address_space(3))) unsigned*)((char*)(RP) + brow*256 + lane*16), \
                16, 0, 0);                                                     \
        } } while (0)

    // read the 4 float4s of one k-step's A fragments (rows l31, 32+l31)
    #define AREAD(RP, S, P0, P1, P2, P3) do {                                  \
        int r0_ = l31, r1_ = 32 + l31;                                         \
        P0 = *(const float4*)((const char*)(RP) + r0_*256 + ((((S)*4 + hs*2    ) ^ (r0_ & 15)) << 4)); \
        P1 = *(const float4*)((const char*)(RP) + r0_*256 + ((((S)*4 + hs*2 + 1) ^ (r0_ & 15)) << 4)); \
        P2 = *(const float4*)((const char*)(RP) + r1_*256 + ((((S)*4 + hs*2    ) ^ (r1_ & 15)) << 4)); \
        P3 = *(const float4*)((const char*)(RP) + r1_*256 + ((((S)*4 + hs*2 + 1) ^ (r1_ & 15)) << 4)); \
    } while (0)

    #define KC(K) ((K) < NKS1 ? (K) : 0)

    #define BLOAD2(KS, H0, H1) do {                                            \
        size_t nb_ = ((size_t)((KS)*8 + w*2))*64 + lane;                       \
        H0 = W1H[nb_]; H1 = W1H[nb_ + 64]; } while (0)

    #define MFMA4(P0, P1, P2, P3) do {                                         \
        short8v ah0 = cvt8(P0, P1);                                            \
        short8v ah1 = cvt8(P2, P3);                                            \
        acc00 = __builtin_amdgcn_mfma_f32_32x32x16_bf16(ah0, b0h0, acc00, 0,0,0); \
        acc01 = __builtin_amdgcn_mfma_f32_32x32x16_bf16(ah0, b0h1, acc01, 0,0,0); \
        acc10 = __builtin_amdgcn_mfma_f32_32x32x16_bf16(ah1, b0h0, acc10, 0,0,0); \
        acc11 = __builtin_amdgcn_mfma_f32_32x32x16_bf16(ah1, b0h1, acc11, 0,0,0); \
    } while (0)

    #define ROTB() do {                                                        \
        b0h0 = b1h0; b0h1 = b1h1; b1h0 = b2h0; b1h1 = b2h1;                    \
        b2h0 = b3h0; b2h1 = b3h1; b3h0 = nb0; b3h1 = nb1; } while (0)

    // one 4-SSTEP chunk: counted wait (never 0), barrier, issue A(C+2),
    // A-frags prefetched 1 SSTEP ahead, B-pipe depth 4.
    #define CHUNK4(RP, C, VMC, DOISS, RISS) do {                               \
        asm volatile("s_waitcnt vmcnt(" #VMC ")" ::: "memory");                \
        __builtin_amdgcn_s_barrier();                                          \
        if (DOISS) AISSUE((C)+2, RISS);                                        \
        float4 p0,p1,p2,p3,q0,q1,q2,q3; short8v nb0, nb1;                      \
        AREAD(RP, 0, p0,p1,p2,p3);                                             \
        BLOAD2(KC((C)*4+4), nb0, nb1); AREAD(RP, 1, q0,q1,q2,q3);              \
        MFMA4(p0,p1,p2,p3); ROTB();                                            \
        BLOAD2(KC((C)*4+5), nb0, nb1); AREAD(RP, 2, p0,p1,p2,p3);              \
        MFMA4(q0,q1,q2,q3); ROTB();                                            \
        BLOAD2(KC((C)*4+6), nb0, nb1); AREAD(RP, 3, q0,q1,q2,q3);              \
        MFMA4(p0,p1,p2,p3); ROTB();                                            \
        BLOAD2(KC((C)*4+7), nb0, nb1);                                         \
        MFMA4(q0,q1,q2,q3); ROTB();                                            \
    } while (0)

    // ---- prologue: A chunks 0,1 in flight; B pipe filled to depth 4 ----
    AISSUE(0, R0);
    AISSUE(1, R1);
    short8v b0h0, b0h1, b1h0, b1h1, b2h0, b2h1, b3h0, b3h1;
    BLOAD2(0, b0h0, b0h1);
    BLOAD2(1, b1h0, b1h1);
    BLOAD2(2, b2h0, b2h1);
    BLOAD2(3, b3h0, b3h1);

    // ================= GEMM1: 6 chunks x 4 k-steps + 1 tail k-step =================
    // vmcnt = loads issued after A(C)'s 4 loads (A:4/chunk, B:8/chunk).
    CHUNK4(R0, 0, 12, true,  R2);   // newer: A1(4) + Bpro(8)
    CHUNK4(R1, 1, 20, true,  R0);   // newer: Bpro(8) + A2(4) + Bc0(8)
    CHUNK4(R2, 2, 20, true,  R1);   // newer: Bc0(8) + A3(4) + Bc1(8)
    CHUNK4(R0, 3, 20, true,  R2);   // ...
    CHUNK4(R1, 4, 20, true,  R0);   // issues A6 -> R0
    CHUNK4(R2, 5, 20, false, R0);
    // tail chunk 6: k-step 24 only (cols 384..399 real)
    {
        asm volatile("s_waitcnt vmcnt(16)" ::: "memory");
        __builtin_amdgcn_s_barrier();
        float4 p0, p1, p2, p3;
        AREAD(R0, 0, p0, p1, p2, p3);
        MFMA4(p0, p1, p2, p3);
    }

    #undef CHUNK4
    #undef ROTB
    #undef MFMA4
    #undef BLOAD2
    #undef KC
    #undef AREAD
    #undef AISSUE

    __syncthreads();   // full drain (one-time); rings reusable as F1h

    // ---- epilogue1: bias + relu + bf16 (hi only) -> F1h (XOR-swizzled) ----
    // F1h rows 0-31 -> R0, rows 32-63 -> R1.
    // C/D layout: col = lane&31, row = (r&3) + 8*(r>>2) + 4*(lane>>5)
    unsigned short* F1hA = (unsigned short*)R0;
    unsigned short* F1hB = (unsigned short*)R1;
    const float b1c0 = b1[w*64 + l31];
    const float b1c1 = b1[w*64 + 32 + l31];
#define EPI1(ACC, FH, NI) do {                                            \
        int gcol = w*64 + (NI)*32 + l31;                                  \
        float bb = (NI) ? b1c1 : b1c0;                                    \
        _Pragma("unroll")                                                 \
        for (int r = 0; r < 16; ++r) {                                    \
            int lrow = (r & 3) + 8*(r >> 2) + 4*hs;   /* 0..31 */         \
            float v = fmaxf(ACC[r] + bb, 0.f);                            \
            int phys = lrow*256 + (((gcol >> 3) ^ lrow) << 3) + (gcol & 7); \
            FH[phys] = f2bf(v);                                           \
        } } while (0)
    EPI1(acc00, F1hA, 0); EPI1(acc01, F1hA, 1); EPI1(acc10, F1hB, 0); EPI1(acc11, F1hB, 1);
#undef EPI1
    __syncthreads();

    // ================= GEMM2: feat2 = relu(feat1 @ W2 + b2) =================
    // A = bf16(feat1) hi-only; B = W2 hi+lo (2 MFMAs per K-step).
    f32x16 acc2;
    #pragma unroll
    for (int r = 0; r < 16; ++r) acc2[r] = 0.f;
    const int m2   = w >> 1;      // node-row half
    const int nt2  = w & 1;       // col half
    const unsigned short* F1rd = m2 ? F1hB : F1hA;   // local rows 0..31 = l31

    const short8v* W2H = (const short8v*)w2h;
    const short8v* W2L = (const short8v*)w2l;
    short8v bhc = W2H[(size_t)nt2*64 + lane];
    short8v blc = W2L[(size_t)nt2*64 + lane];
    #pragma unroll
    for (int ks = 0; ks < NKS2; ++ks) {
        short8v bhn = bhc, bln = blc;
        if (ks + 1 < NKS2) {
            size_t nbase = (size_t)((ks + 1)*2 + nt2)*64 + lane;
            bhn = W2H[nbase];
            bln = W2L[nbase];
        }
        int blk  = (ks*2 + hs) ^ l31;
        short8v ah2 = *(const short8v*)&F1rd[l31*256 + blk*8];
        acc2 = __builtin_amdgcn_mfma_f32_32x32x16_bf16(ah2, bhc, acc2, 0,0,0);
        acc2 = __builtin_amdgcn_mfma_f32_32x32x16_bf16(ah2, blc, acc2, 0,0,0);
        bhc = bhn; blc = bln;
    }
    __syncthreads();   // all F1 reads done

    // ---- epilogue2: s_n = relu(feat2 + b2) . Wout, 32-col shfl reduce ----
    float* s2p  = R2;          // 128 floats
    float* srow = R2 + 128;    // 64 floats
    {
        const int   col2 = nt2*32 + l31;
        const float b2c  = b2[col2];
        const float woc  = Wout[col2];
        #pragma unroll
        for (int r = 0; r < 16; ++r) {
            float v = fmaxf(acc2[r] + b2c, 0.f) * woc;
            v += __shfl_xor(v, 1);
            v += __shfl_xor(v, 2);
            v += __shfl_xor(v, 4);
            v += __shfl_xor(v, 8);
            v += __shfl_xor(v, 16);
            if (l31 == 0) {
                int grow = m2*32 + (r & 3) + 8*(r >> 2) + 4*hs;
                s2p[nt2*64 + grow] = v;   // [colhalf][row]
            }
        }
    }
    __syncthreads();
    if (t < 64) srow[t] = s2p[t] + s2p[64 + t];
    __syncthreads();

    // ---- segmented sum over sorted batch, one atomic per run ----
    if (t < 64) {
        int node = n0 + t;
        int b = (node < N) ? batch[node] : -1;
        int pb = (t == 0) ? -2 : ((node - 1 < N) ? batch[node - 1] : -1);
        if (b >= 0 && b != pb) {
            float acc = 0.f;
            int j = t;
            while (j < 64 && (n0 + j) < N && batch[n0 + j] == b) { acc += srow[j]; ++j; }
            atomicAdd(&gf1d[b], acc);
        }
    }
}

__global__ void final_sigmoid(const float* __restrict__ gf1d, const float* __restrict__ bout,
                              float* __restrict__ out, int G)
{
    int g = blockIdx.x * 256 + threadIdx.x;
    if (g < G) out[g] = 1.f / (1.f + expf(-(gf1d[g] + bout[0])));
}

extern "C" void kernel_launch(void* const* d_in, const int* in_sizes, int n_in,
                              void* d_out, int out_size, void* d_ws, size_t ws_size,
                              hipStream_t stream)
{
    const float* h    = (const float*)d_in[0];
    const float* x    = (const float*)d_in[1];
    const int*   batch= (const int*)d_in[2];
    const float* W1   = (const float*)d_in[3];
    const float* b1   = (const float*)d_in[4];
    const float* W2   = (const float*)d_in[5];
    const float* b2   = (const float*)d_in[6];
    const float* Wout = (const float*)d_in[7];
    const float* bout = (const float*)d_in[8];
    float* out = (float*)d_out;

    const int N = in_sizes[2];
    const int G = out_size;

    // workspace layout (~280 KB total)
    char* ws = (char*)d_ws;
    float* gf1d = (float*)ws;                                  //   8,192 B
    float* zbuf = (float*)(ws + 8192);                         //   1,024 B (zeros)
    unsigned short* w1h = (unsigned short*)(ws + 9216);        // 204,800 B
    unsigned short* w2h = w1h + (size_t)W1P_SH8 * 8;           //  32,768 B
    unsigned short* w2l = w2h + (size_t)W2P_SH8 * 8;           //  32,768 B

    hipMemsetAsync(gf1d, 0, 9216, stream);   // gf accumulators + zero buffer
    pack_weights<<<(W1P_SH8 + W2P_SH8 + 255) / 256, 256, 0, stream>>>(W1, W2, w1h, w2h, w2l);
    fused_readout<<<(N + BM - 1) / BM, 256, 0, stream>>>(h, x, batch, w1h, w2h, w2l,
                                                         b1, b2, Wout, zbuf, gf1d, N);
    final_sigmoid<<<(G + 255) / 256, 256, 0, stream>>>(gf1d, bout, out, G);
}